// Round 8
// baseline (151.151 us; speedup 1.0000x reference)
//
#include <hip/hip_runtime.h>
#include <hip/hip_bf16.h>
#include <math.h>

typedef __attribute__((ext_vector_type(8))) __bf16 bf16x8;
typedef __attribute__((ext_vector_type(4))) float f32x4;

#define NTOK 8192
#define DIN 1024
#define DOUT 1024
#define KAUG 4096
#define SEH 32

#define BK 64
#define KHALF 2048
#define NKT (KHALF / BK)  // 32

static __device__ __forceinline__ unsigned short f2bf(float f) {
  union { float f; unsigned u; } v; v.f = f;
  unsigned r = (v.u + 0x7FFFu + ((v.u >> 16) & 1u)) >> 16;
  return (unsigned short)r;
}

// 4 augmented features for one x: {x, b0/s, b1/s, b2/s} packed as 2 u32 (4 bf16)
static __device__ __forceinline__ uint2 feat4(float v) {
  const float d0 = fabsf(v + 1.f), d1 = fabsf(v), d2 = fabsf(v - 1.f);
  const float b0 = (d0 < 1.f) ? (1.f - d0) * (1.f - d0) : 0.f;
  const float b1 = (d1 < 1.f) ? (1.f - d1) * (1.f - d1) : 0.f;
  const float b2 = (d2 < 1.f) ? (1.f - d2) * (1.f - d2) : 0.f;
  const float inv = __builtin_amdgcn_rcpf(b0 + b1 + b2 + 1e-6f);
  uint2 r;
  r.x = (unsigned)f2bf(v) | ((unsigned)f2bf(b0 * inv) << 16);
  r.y = (unsigned)f2bf(b1 * inv) | ((unsigned)f2bf(b2 * inv) << 16);
  return r;
}

// W_aug[o][i*4 + {0..3}] = { base_w[o,i], spline_w[o,i,0..2] }  (bf16)
__global__ __launch_bounds__(256) void pack_w(const float* __restrict__ bw,
                                              const float* __restrict__ sw,
                                              ushort* __restrict__ Waug) {
  const int id = blockIdx.x * 256 + threadIdx.x;
  ushort4 o;
  o.x = f2bf(bw[id]);
  o.y = f2bf(sw[id * 3 + 0]);
  o.z = f2bf(sw[id * 3 + 1]);
  o.w = f2bf(sw[id * 3 + 2]);
  ((ushort4*)Waug)[id] = o;
}

__global__ __launch_bounds__(256) void pack_se(const float* __restrict__ w1,
                                               const float* __restrict__ w2,
                                               ushort* __restrict__ w1b,
                                               ushort* __restrict__ w2b) {
  const int id = blockIdx.x * 256 + threadIdx.x;
  if (id < SEH * DOUT) w1b[id] = f2bf(w1[id]);
  else w2b[id - SEH * DOUT] = f2bf(w2[id - SEH * DOUT]);
}

#define WAITVM_LG(N) asm volatile("s_waitcnt vmcnt(" #N ") lgkmcnt(0)" ::: "memory")

// Split-K GEMM with FUSED A-augmentation: A-tile staged by loading raw x (f32),
// computing the KAN basis in-register, ds_write_b128 into the swizzled LDS slots
// (identical layout to the old Aaug global_load_lds path). B via global_load_lds.
// R7-validated sync skeleton: all LDS writes at/before the entry wait; entry
// wait = vmcnt(8) lgkmcnt(0); exit barrier before buffer flip.
__global__ __launch_bounds__(512, 2) void gemm_fused(const float* __restrict__ x,
                                                     const ushort* __restrict__ B,
                                                     float* __restrict__ P0,
                                                     float* __restrict__ P1) {
  __shared__ ushort As[2][256 * BK];
  __shared__ ushort Bs[2][256 * BK];
  const int tid = threadIdx.x;
  const int wid = tid >> 6, lane = tid & 63;
  const int l16 = lane & 15, lk = lane >> 4;
  const int wm = wid >> 2, wn = wid & 3;

  const int g = (blockIdx.x & 7) * 32 + (blockIdx.x >> 3);
  const int kh = g >> 7;
  const int bm = (g & 127) >> 2;
  const int bn = g & 3;

  const float* Xb = x + (size_t)bm * 256 * DIN + (size_t)kh * (KHALF / 4);
  const ushort* Bb = B + (size_t)bn * 256 * KAUG + kh * KHALF;
  float* P = kh ? P1 : P0;

  const int lrow = lane >> 3;
  const int lcb = (lane & 7) ^ lrow;  // inverse-swizzled source col-block

  f32x4 acc[8][4] = {};

  // x load for A chunk r of K-tile kt: row r*64+wid*8+lrow, 2 f32 inputs
#define XLOAD(kt, r) \
  (*(const float2*)&Xb[(size_t)((r) * 64 + wid * 8 + lrow) * DIN + (kt) * 16 + lcb * 2])
  // basis + LDS write for chunk r (same slot the old global_load_lds used)
#define AWRITE(buf, r, xv)                                              \
  do {                                                                  \
    const uint2 f0 = feat4((xv).x), f1 = feat4((xv).y);                 \
    uint4 wv; wv.x = f0.x; wv.y = f0.y; wv.z = f1.x; wv.w = f1.y;       \
    *(uint4*)&As[buf][((r) * 512 + wid * 64 + lane) * 8] = wv;          \
  } while (0)

#define STAGE_B(kt, buf, r)                                                     \
  __builtin_amdgcn_global_load_lds(                                             \
      (const __attribute__((address_space(1))) void*)(Bb +                      \
          (size_t)((r) * 64 + wid * 8 + lrow) * KAUG + (kt) * BK + lcb * 8),    \
      (__attribute__((address_space(3))) void*)(&Bs[buf][((r) * 512 + wid * 64) * 8]), \
      16, 0, 0)
#define STAGE_B4(kt, buf)                                                       \
  do { STAGE_B(kt, buf, 0); STAGE_B(kt, buf, 1); STAGE_B(kt, buf, 2); STAGE_B(kt, buf, 3); } while (0)

#define RD_A(buf, m, kk) \
  (*(const bf16x8*)&As[buf][(wm * 128 + (m) * 16 + l16) * 64 + ((((kk) * 4 + lk) ^ (l16 & 7)) << 3)])
#define RD_B(buf, n, kk) \
  (*(const bf16x8*)&Bs[buf][(wn * 64 + (n) * 16 + l16) * 64 + ((((kk) * 4 + lk) ^ (l16 & 7)) << 3)])

  // prologue: stage tile 0 into buf 0 (x loads first, then B -> x consumable at vmcnt(4))
  {
    float2 x0 = XLOAD(0, 0), x1 = XLOAD(0, 1), x2 = XLOAD(0, 2), x3 = XLOAD(0, 3);
    STAGE_B4(0, 0);
    AWRITE(0, 0, x0); AWRITE(0, 1, x1); AWRITE(0, 2, x2); AWRITE(0, 3, x3);
  }

  int bc = 0;
  for (int kt = 0; kt < NKT; ++kt) {
    const bool pf = (kt < NKT - 1);
    float2 xn0, xn1, xn2, xn3;
    if (pf) {
      // issue-early: x loads for tile kt+1, then B stages for tile kt+1
      xn0 = XLOAD(kt + 1, 0); xn1 = XLOAD(kt + 1, 1);
      xn2 = XLOAD(kt + 1, 2); xn3 = XLOAD(kt + 1, 3);
      STAGE_B4(kt + 1, bc ^ 1);
      WAITVM_LG(8);  // drains B(kt) + my A ds_writes(kt); x(kt+1)+B(kt+1) fly
    } else {
      WAITVM_LG(0);
    }
    __builtin_amdgcn_s_barrier();        // entry: tile kt visible to all waves
    __builtin_amdgcn_sched_barrier(0);   // pin reads below the sync point

    bf16x8 af[8][2], bfr[4][2];
#pragma unroll
    for (int m = 0; m < 8; ++m) { af[m][0] = RD_A(bc, m, 0); af[m][1] = RD_A(bc, m, 1); }
#pragma unroll
    for (int n = 0; n < 4; ++n) { bfr[n][0] = RD_B(bc, n, 0); bfr[n][1] = RD_B(bc, n, 1); }

    __builtin_amdgcn_s_setprio(1);
#pragma unroll
    for (int k2 = 0; k2 < 2; ++k2)
#pragma unroll
      for (int m = 0; m < 8; ++m)
#pragma unroll
        for (int n = 0; n < 4; ++n)
          acc[m][n] = __builtin_amdgcn_mfma_f32_16x16x32_bf16(af[m][k2], bfr[n][k2], acc[m][n], 0, 0, 0);
    __builtin_amdgcn_s_setprio(0);

    // write-late: basis for tile kt+1 into buf^1 (x latency hidden under MFMAs)
    if (pf) {
      AWRITE(bc ^ 1, 0, xn0); AWRITE(bc ^ 1, 1, xn1);
      AWRITE(bc ^ 1, 2, xn2); AWRITE(bc ^ 1, 3, xn3);
    }

    __builtin_amdgcn_s_barrier();        // exit: reads retired before buf reuse
    bc ^= 1;
  }

  // C/D layout: col = lane&15, row = (lane>>4)*4 + reg
  float* Cb = P + (size_t)(bm * 256 + wm * 128) * DOUT + bn * 256 + wn * 64;
#pragma unroll
  for (int m = 0; m < 8; ++m)
#pragma unroll
    for (int n = 0; n < 4; ++n)
#pragma unroll
      for (int j = 0; j < 4; ++j)
        Cb[(size_t)(m * 16 + lk * 4 + j) * DOUT + n * 16 + l16] = acc[m][n][j];
}

// Fused partial-sum + LayerNorm + SE (both SE matmuls on MFMA).
// 16 tokens/block, 4 waves. Y kept f32 in LDS; weights bf16 read from L2.
__global__ __launch_bounds__(256) void ln_se_mfma(
    float* __restrict__ out, const float* __restrict__ p1,
    const float* __restrict__ ln_w, const float* __restrict__ ln_b,
    const ushort* __restrict__ w1b, const float* __restrict__ se_b1,
    const ushort* __restrict__ w2b, const float* __restrict__ se_b2) {
  __shared__ float Yl[16 * 1028];       // 16 tokens x 1024 (+4 pad) f32
  __shared__ float Hpart[4][512];       // per-wave SE1 partials (16x32)
  __shared__ unsigned Hb[256];          // H packed bf16 [16 tok][16 u32]
  const int tid = threadIdx.x;
  const int w = tid >> 6, lane = tid & 63;
  const int l16 = lane & 15, lk = lane >> 4;
  const int tok0 = blockIdx.x * 16;

  float lw[16], lb[16];
#pragma unroll
  for (int e = 0; e < 16; ++e) {
    lw[e] = ln_w[e * 64 + lane];
    lb[e] = ln_b[e * 64 + lane];
  }

  for (int q = 0; q < 4; ++q) {
    const int tl = w * 4 + q;
    const float* r0 = out + (size_t)(tok0 + tl) * DOUT;
    const float* r1 = p1 + (size_t)(tok0 + tl) * DOUT;
    float v[16];
#pragma unroll
    for (int e = 0; e < 16; ++e) v[e] = r0[e * 64 + lane] + r1[e * 64 + lane];
    float s = 0.f, ss = 0.f;
#pragma unroll
    for (int e = 0; e < 16; ++e) { s += v[e]; ss += v[e] * v[e]; }
#pragma unroll
    for (int m = 32; m; m >>= 1) { s += __shfl_xor(s, m); ss += __shfl_xor(ss, m); }
    const float mu = s * (1.f / (float)DOUT);
    const float inv = rsqrtf(ss * (1.f / (float)DOUT) - mu * mu + 1e-5f);
#pragma unroll
    for (int e = 0; e < 16; ++e)
      Yl[tl * 1028 + e * 64 + lane] = (v[e] - mu) * inv * lw[e] + lb[e];
  }
  __syncthreads();

  // SE1: H[16 tok][32 hid] = Y[16][1024] @ w1^T. K split across waves (256 each).
  f32x4 acc1[2] = {};
#pragma unroll
  for (int s = 0; s < 8; ++s) {
    const int ks = w * 8 + s;
    const int k = ks * 32 + lk * 8;
    const float* yp = &Yl[l16 * 1028 + k];
    const f32x4 q0 = *(const f32x4*)yp;
    const f32x4 q1 = *(const f32x4*)(yp + 4);
    bf16x8 af;
    af[0] = (__bf16)q0[0]; af[1] = (__bf16)q0[1];
    af[2] = (__bf16)q0[2]; af[3] = (__bf16)q0[3];
    af[4] = (__bf16)q1[0]; af[5] = (__bf16)q1[1];
    af[6] = (__bf16)q1[2]; af[7] = (__bf16)q1[3];
#pragma unroll
    for (int nt = 0; nt < 2; ++nt) {
      const bf16x8 bf = *(const bf16x8*)(w1b + (nt * 16 + l16) * 1024 + ks * 32 + lk * 8);
      acc1[nt] = __builtin_amdgcn_mfma_f32_16x16x32_bf16(af, bf, acc1[nt], 0, 0, 0);
    }
  }
#pragma unroll
  for (int nt = 0; nt < 2; ++nt)
#pragma unroll
    for (int j = 0; j < 4; ++j)
      Hpart[w][(lk * 4 + j) * 32 + nt * 16 + l16] = acc1[nt][j];
  __syncthreads();

  {
    const int e2 = tid * 2;
    float h0 = Hpart[0][e2] + Hpart[1][e2] + Hpart[2][e2] + Hpart[3][e2];
    float h1 = Hpart[0][e2 + 1] + Hpart[1][e2 + 1] + Hpart[2][e2 + 1] + Hpart[3][e2 + 1];
    h0 = fmaxf(h0 + se_b1[e2 & 31], 0.f);
    h1 = fmaxf(h1 + se_b1[(e2 & 31) + 1], 0.f);
    Hb[tid] = (unsigned)f2bf(h0) | ((unsigned)f2bf(h1) << 16);
  }
  __syncthreads();

  // SE2: G[16 tok][1024] = H[16][32] @ w2^T, N split across waves (256 each).
  union { uint4 u; bf16x8 v; } ha;
  ha.u = *(const uint4*)&Hb[l16 * 16 + lk * 4];
  const int nbase = w * 256;
#pragma unroll
  for (int nt = 0; nt < 16; ++nt) {
    const int col = nbase + nt * 16 + l16;
    const bf16x8 bf = *(const bf16x8*)(w2b + col * 32 + lk * 8);
    f32x4 gz = {0.f, 0.f, 0.f, 0.f};
    gz = __builtin_amdgcn_mfma_f32_16x16x32_bf16(ha.v, bf, gz, 0, 0, 0);
    const float b2 = se_b2[col];
#pragma unroll
    for (int j = 0; j < 4; ++j) {
      const int tl = lk * 4 + j;
      const float sg = 1.f / (1.f + __expf(-(gz[j] + b2)));
      out[(size_t)(tok0 + tl) * DOUT + col] = Yl[tl * 1028 + col] * sg;
    }
  }
}

extern "C" void kernel_launch(void* const* d_in, const int* in_sizes, int n_in,
                              void* d_out, int out_size, void* d_ws, size_t ws_size,
                              hipStream_t stream) {
  const float* x = (const float*)d_in[0];
  const float* bw = (const float*)d_in[1];
  const float* sw = (const float*)d_in[2];
  const float* ln_w = (const float*)d_in[3];
  const float* ln_b = (const float*)d_in[4];
  const float* se_w1 = (const float*)d_in[5];
  const float* se_b1 = (const float*)d_in[6];
  const float* se_w2 = (const float*)d_in[7];
  const float* se_b2 = (const float*)d_in[8];
  float* out = (float*)d_out;

  ushort* Waug = (ushort*)d_ws;                        // 8 MB
  ushort* w1b = Waug + (size_t)DOUT * KAUG;            // 64 KB
  ushort* w2b = w1b + SEH * DOUT;                      // 64 KB
  float* P1 = (float*)(w2b + SEH * DOUT);              // 32 MB (K-half-1 partial)

  pack_w<<<DOUT * DIN / 256, 256, 0, stream>>>(bw, sw, Waug);
  pack_se<<<2 * SEH * DOUT / 256, 256, 0, stream>>>(se_w1, se_w2, w1b, w2b);
  gemm_fused<<<256, 512, 0, stream>>>(x, Waug, out, P1);
  ln_se_mfma<<<NTOK / 16, 256, 0, stream>>>(out, P1, ln_w, ln_b, w1b, se_b1, w2b, se_b2);
}

// Round 9
// 138.341 us; speedup vs baseline: 1.0926x; 1.0926x over previous
//
#include <hip/hip_runtime.h>
#include <hip/hip_bf16.h>
#include <math.h>

typedef __attribute__((ext_vector_type(8))) __bf16 bf16x8;
typedef __attribute__((ext_vector_type(4))) float f32x4;

#define NTOK 8192
#define DIN 1024
#define DOUT 1024
#define KAUG 4096
#define SEH 32

#define BK 64
#define KHALF 2048
#define NKT (KHALF / BK)  // 32

static __device__ __forceinline__ unsigned short f2bf(float f) {
  union { float f; unsigned u; } v; v.f = f;
  unsigned r = (v.u + 0x7FFFu + ((v.u >> 16) & 1u)) >> 16;
  return (unsigned short)r;
}
static __device__ __forceinline__ float bflo(unsigned u) {
  union { unsigned u; float f; } v; v.u = u << 16; return v.f;
}
static __device__ __forceinline__ float bfhi(unsigned u) {
  union { unsigned u; float f; } v; v.u = u & 0xFFFF0000u; return v.f;
}

// Merged prep: build_aaug (32768 blocks) + pack_w (4096) + pack_se (256).
__global__ __launch_bounds__(256) void prep(const float* __restrict__ x,
                                            const float* __restrict__ bw,
                                            const float* __restrict__ sw,
                                            const float* __restrict__ w1,
                                            const float* __restrict__ w2,
                                            ushort* __restrict__ Aaug,
                                            ushort* __restrict__ Waug,
                                            ushort* __restrict__ w1b,
                                            ushort* __restrict__ w2b) {
  const int b = blockIdx.x;
  if (b < 32768) {
    const int id = b * 256 + threadIdx.x;  // over NTOK*DIN
    const float v = x[id];
    const float d0 = fabsf(v + 1.f), d1 = fabsf(v), d2 = fabsf(v - 1.f);
    float b0 = (d0 < 1.f) ? (1.f - d0) * (1.f - d0) : 0.f;
    float b1 = (d1 < 1.f) ? (1.f - d1) * (1.f - d1) : 0.f;
    float b2 = (d2 < 1.f) ? (1.f - d2) * (1.f - d2) : 0.f;
    const float inv = 1.f / (b0 + b1 + b2 + 1e-6f);
    ushort4 o;
    o.x = f2bf(v);
    o.y = f2bf(b0 * inv);
    o.z = f2bf(b1 * inv);
    o.w = f2bf(b2 * inv);
    ((ushort4*)Aaug)[id] = o;
  } else if (b < 32768 + 4096) {
    const int id = (b - 32768) * 256 + threadIdx.x;  // over DOUT*DIN
    ushort4 o;
    o.x = f2bf(bw[id]);
    o.y = f2bf(sw[id * 3 + 0]);
    o.z = f2bf(sw[id * 3 + 1]);
    o.w = f2bf(sw[id * 3 + 2]);
    ((ushort4*)Waug)[id] = o;
  } else {
    const int id = (b - 32768 - 4096) * 256 + threadIdx.x;  // 0..65535
    if (id < SEH * DOUT) w1b[id] = f2bf(w1[id]);
    else w2b[id - SEH * DOUT] = f2bf(w2[id - SEH * DOUT]);
  }
}

#define WAITVM(N) asm volatile("s_waitcnt vmcnt(" #N ")" ::: "memory")

// Split-K GEMM: C-tile 256x256, K split in 2 halves of 2048.
// 8 waves (2M x 4N), per-wave 128x64 (acc[8][4]). Double-buffered 128KB LDS.
// R7-validated sync skeleton. New: bf16 partial outputs; K-loop unrolled x2 with
// compile-time LDS buffer + precomputed swizzle lane-constants so every ds_read
// is base-reg + immediate offset.
__global__ __launch_bounds__(512, 2) void gemm_sk(const ushort* __restrict__ A,
                                                  const ushort* __restrict__ B,
                                                  ushort* __restrict__ P0,
                                                  ushort* __restrict__ P1) {
  __shared__ ushort As[2][256 * BK];
  __shared__ ushort Bs[2][256 * BK];
  const int tid = threadIdx.x;
  const int wid = tid >> 6, lane = tid & 63;
  const int l16 = lane & 15, lk = lane >> 4;
  const int wm = wid >> 2, wn = wid & 3;

  const int g = (blockIdx.x & 7) * 32 + (blockIdx.x >> 3);
  const int kh = g >> 7;
  const int bm = (g & 127) >> 2;
  const int bn = g & 3;

  const ushort* Ab = A + (size_t)bm * 256 * KAUG + kh * KHALF;
  const ushort* Bb = B + (size_t)bn * 256 * KAUG + kh * KHALF;
  ushort* P = kh ? P1 : P0;

  const int lrow = lane >> 3;
  const int lcb = (lane & 7) ^ lrow;

  // ds_read lane constants (element units):
  //  index = base + m*1024 + sw(kk), sw1 = sw0^32  [verified algebra of the
  //  involution ((kk*4+lk)^(l16&7))<<3 ]
  const int aBase = (wm * 128 + l16) * 64;
  const int bBase = (wn * 64 + l16) * 64;
  const int sw0 = ((l16 & 4) << 3) + ((lk ^ (l16 & 3)) << 3);
  const int sw1 = sw0 ^ 32;

  f32x4 acc[8][4] = {};

#define STAGE_A(kt, buf, r)                                                     \
  __builtin_amdgcn_global_load_lds(                                             \
      (const __attribute__((address_space(1))) void*)(Ab +                      \
          (size_t)((r) * 64 + wid * 8 + lrow) * KAUG + (kt) * BK + lcb * 8),    \
      (__attribute__((address_space(3))) void*)(&As[buf][((r) * 512 + wid * 64) * 8]), \
      16, 0, 0)
#define STAGE_B(kt, buf, r)                                                     \
  __builtin_amdgcn_global_load_lds(                                             \
      (const __attribute__((address_space(1))) void*)(Bb +                      \
          (size_t)((r) * 64 + wid * 8 + lrow) * KAUG + (kt) * BK + lcb * 8),    \
      (__attribute__((address_space(3))) void*)(&Bs[buf][((r) * 512 + wid * 64) * 8]), \
      16, 0, 0)
#define STAGE_ALL(kt, buf)                                                      \
  do {                                                                          \
    STAGE_A(kt, buf, 0); STAGE_A(kt, buf, 1); STAGE_A(kt, buf, 2); STAGE_A(kt, buf, 3); \
    STAGE_B(kt, buf, 0); STAGE_B(kt, buf, 1); STAGE_B(kt, buf, 2); STAGE_B(kt, buf, 3); \
  } while (0)

  // One K-tile: CB = compute buffer (compile-time), NB = stage buffer.
#define TILE(kt, CB, NB)                                                        \
  do {                                                                          \
    if ((kt) < NKT - 1) {                                                       \
      STAGE_ALL((kt) + 1, NB);                                                  \
      WAITVM(8);                                                                \
    } else {                                                                    \
      WAITVM(0);                                                                \
    }                                                                           \
    __builtin_amdgcn_s_barrier();                                               \
    __builtin_amdgcn_sched_barrier(0);                                          \
    bf16x8 af[8][2], bfr[4][2];                                                 \
    _Pragma("unroll")                                                           \
    for (int m = 0; m < 8; ++m) {                                               \
      af[m][0] = *(const bf16x8*)&As[CB][aBase + m * 1024 + sw0];               \
      af[m][1] = *(const bf16x8*)&As[CB][aBase + m * 1024 + sw1];               \
    }                                                                           \
    _Pragma("unroll")                                                           \
    for (int n = 0; n < 4; ++n) {                                               \
      bfr[n][0] = *(const bf16x8*)&Bs[CB][bBase + n * 1024 + sw0];              \
      bfr[n][1] = *(const bf16x8*)&Bs[CB][bBase + n * 1024 + sw1];              \
    }                                                                           \
    __builtin_amdgcn_s_setprio(1);                                              \
    _Pragma("unroll")                                                           \
    for (int k2 = 0; k2 < 2; ++k2)                                              \
      _Pragma("unroll")                                                         \
      for (int m = 0; m < 8; ++m)                                               \
        _Pragma("unroll")                                                       \
        for (int n = 0; n < 4; ++n)                                             \
          acc[m][n] = __builtin_amdgcn_mfma_f32_16x16x32_bf16(                  \
              af[m][k2], bfr[n][k2], acc[m][n], 0, 0, 0);                       \
    __builtin_amdgcn_s_setprio(0);                                              \
    __builtin_amdgcn_s_barrier();                                               \
  } while (0)

  // prologue: stage tile 0 into buf 0
  STAGE_ALL(0, 0);

  for (int kt2 = 0; kt2 < NKT; kt2 += 2) {
    TILE(kt2, 0, 1);
    TILE(kt2 + 1, 1, 0);
  }

  // C/D layout: col = lane&15, row = (lane>>4)*4 + reg; store bf16 partials
  ushort* Cb = P + (size_t)(bm * 256 + wm * 128) * DOUT + bn * 256 + wn * 64;
#pragma unroll
  for (int m = 0; m < 8; ++m)
#pragma unroll
    for (int n = 0; n < 4; ++n)
#pragma unroll
      for (int j = 0; j < 4; ++j)
        Cb[(size_t)(m * 16 + lk * 4 + j) * DOUT + n * 16 + l16] = f2bf(acc[m][n][j]);
}

// Fused partial-sum (bf16) + LayerNorm + SE (both SE matmuls on MFMA).
// 16 tokens/block, 4 waves. Y kept f32 in LDS; weights bf16 read from L2.
__global__ __launch_bounds__(256) void ln_se_mfma(
    float* __restrict__ out,
    const ushort* __restrict__ p0, const ushort* __restrict__ p1,
    const float* __restrict__ ln_w, const float* __restrict__ ln_b,
    const ushort* __restrict__ w1b, const float* __restrict__ se_b1,
    const ushort* __restrict__ w2b, const float* __restrict__ se_b2) {
  __shared__ float Yl[16 * 1028];       // 16 tokens x 1024 (+4 pad) f32
  __shared__ float Hpart[4][512];       // per-wave SE1 partials (16x32)
  __shared__ unsigned Hb[256];          // H packed bf16 [16 tok][16 u32]
  const int tid = threadIdx.x;
  const int w = tid >> 6, lane = tid & 63;
  const int l16 = lane & 15, lk = lane >> 4;
  const int tok0 = blockIdx.x * 16;

  // lane owns col pairs {2u, 2u+1}, u = q*64+lane, q=0..7
  float2 lwp[8], lbp[8];
#pragma unroll
  for (int q = 0; q < 8; ++q) {
    lwp[q] = ((const float2*)ln_w)[q * 64 + lane];
    lbp[q] = ((const float2*)ln_b)[q * 64 + lane];
  }

  for (int qt = 0; qt < 4; ++qt) {
    const int tl = w * 4 + qt;
    const uint* r0 = (const uint*)(p0 + (size_t)(tok0 + tl) * DOUT);
    const uint* r1 = (const uint*)(p1 + (size_t)(tok0 + tl) * DOUT);
    float v0[8], v1[8];
#pragma unroll
    for (int q = 0; q < 8; ++q) {
      const uint a = r0[q * 64 + lane], b = r1[q * 64 + lane];
      v0[q] = bflo(a) + bflo(b);
      v1[q] = bfhi(a) + bfhi(b);
    }
    float s = 0.f, ss = 0.f;
#pragma unroll
    for (int q = 0; q < 8; ++q) {
      s += v0[q] + v1[q];
      ss += v0[q] * v0[q] + v1[q] * v1[q];
    }
#pragma unroll
    for (int m = 32; m; m >>= 1) { s += __shfl_xor(s, m); ss += __shfl_xor(ss, m); }
    const float mu = s * (1.f / (float)DOUT);
    const float inv = rsqrtf(ss * (1.f / (float)DOUT) - mu * mu + 1e-5f);
#pragma unroll
    for (int q = 0; q < 8; ++q) {
      float2 y2;
      y2.x = (v0[q] - mu) * inv * lwp[q].x + lbp[q].x;
      y2.y = (v1[q] - mu) * inv * lwp[q].y + lbp[q].y;
      *(float2*)&Yl[tl * 1028 + (q * 64 + lane) * 2] = y2;
    }
  }
  __syncthreads();

  // SE1: H[16 tok][32 hid] = Y[16][1024] @ w1^T. K split across waves (256 each).
  f32x4 acc1[2] = {};
#pragma unroll
  for (int s = 0; s < 8; ++s) {
    const int ks = w * 8 + s;
    const int k = ks * 32 + lk * 8;
    const float* yp = &Yl[l16 * 1028 + k];
    const f32x4 q0 = *(const f32x4*)yp;
    const f32x4 q1 = *(const f32x4*)(yp + 4);
    bf16x8 af;
    af[0] = (__bf16)q0[0]; af[1] = (__bf16)q0[1];
    af[2] = (__bf16)q0[2]; af[3] = (__bf16)q0[3];
    af[4] = (__bf16)q1[0]; af[5] = (__bf16)q1[1];
    af[6] = (__bf16)q1[2]; af[7] = (__bf16)q1[3];
#pragma unroll
    for (int nt = 0; nt < 2; ++nt) {
      const bf16x8 bf = *(const bf16x8*)(w1b + (nt * 16 + l16) * 1024 + ks * 32 + lk * 8);
      acc1[nt] = __builtin_amdgcn_mfma_f32_16x16x32_bf16(af, bf, acc1[nt], 0, 0, 0);
    }
  }
#pragma unroll
  for (int nt = 0; nt < 2; ++nt)
#pragma unroll
    for (int j = 0; j < 4; ++j)
      Hpart[w][(lk * 4 + j) * 32 + nt * 16 + l16] = acc1[nt][j];
  __syncthreads();

  {
    const int e2 = tid * 2;
    float h0 = Hpart[0][e2] + Hpart[1][e2] + Hpart[2][e2] + Hpart[3][e2];
    float h1 = Hpart[0][e2 + 1] + Hpart[1][e2 + 1] + Hpart[2][e2 + 1] + Hpart[3][e2 + 1];
    h0 = fmaxf(h0 + se_b1[e2 & 31], 0.f);
    h1 = fmaxf(h1 + se_b1[(e2 & 31) + 1], 0.f);
    Hb[tid] = (unsigned)f2bf(h0) | ((unsigned)f2bf(h1) << 16);
  }
  __syncthreads();

  // SE2: G[16 tok][1024] = H[16][32] @ w2^T, N split across waves (256 each).
  union { uint4 u; bf16x8 v; } ha;
  ha.u = *(const uint4*)&Hb[l16 * 16 + lk * 4];
  const int nbase = w * 256;
#pragma unroll
  for (int nt = 0; nt < 16; ++nt) {
    const int col = nbase + nt * 16 + l16;
    const bf16x8 bf = *(const bf16x8*)(w2b + col * 32 + lk * 8);
    f32x4 gz = {0.f, 0.f, 0.f, 0.f};
    gz = __builtin_amdgcn_mfma_f32_16x16x32_bf16(ha.v, bf, gz, 0, 0, 0);
    const float b2 = se_b2[col];
#pragma unroll
    for (int j = 0; j < 4; ++j) {
      const int tl = lk * 4 + j;
      const float sg = 1.f / (1.f + __expf(-(gz[j] + b2)));
      out[(size_t)(tok0 + tl) * DOUT + col] = Yl[tl * 1028 + col] * sg;
    }
  }
}

extern "C" void kernel_launch(void* const* d_in, const int* in_sizes, int n_in,
                              void* d_out, int out_size, void* d_ws, size_t ws_size,
                              hipStream_t stream) {
  const float* x = (const float*)d_in[0];
  const float* bw = (const float*)d_in[1];
  const float* sw = (const float*)d_in[2];
  const float* ln_w = (const float*)d_in[3];
  const float* ln_b = (const float*)d_in[4];
  const float* se_w1 = (const float*)d_in[5];
  const float* se_b1 = (const float*)d_in[6];
  const float* se_w2 = (const float*)d_in[7];
  const float* se_b2 = (const float*)d_in[8];
  float* out = (float*)d_out;

  ushort* Aaug = (ushort*)d_ws;                        // 64 MB
  ushort* Waug = Aaug + (size_t)NTOK * KAUG;           // 8 MB
  ushort* w1b = Waug + (size_t)DOUT * KAUG;            // 64 KB
  ushort* w2b = w1b + SEH * DOUT;                      // 64 KB
  ushort* P0b = w2b + SEH * DOUT;                      // 16 MB (K-half-0, bf16)
  ushort* P1b = P0b + (size_t)NTOK * DOUT;             // 16 MB (K-half-1, bf16)

  prep<<<32768 + 4096 + 256, 256, 0, stream>>>(x, bw, sw, se_w1, se_w2,
                                               Aaug, Waug, w1b, w2b);
  gemm_sk<<<256, 512, 0, stream>>>(Aaug, Waug, P0b, P1b);
  ln_se_mfma<<<NTOK / 16, 256, 0, stream>>>(out, P0b, P1b, ln_w, ln_b,
                                            w1b, se_b1, w2b, se_b2);
}

// Round 10
// 108.267 us; speedup vs baseline: 1.3961x; 1.2778x over previous
//
#include <hip/hip_runtime.h>
#include <hip/hip_bf16.h>
#include <math.h>

typedef __attribute__((ext_vector_type(8))) __bf16 bf16x8;
typedef __attribute__((ext_vector_type(4))) float f32x4;

#define NTOK 8192
#define DIN 1024
#define DOUT 1024
#define KAUG 4096
#define SEH 32

#define BK 64
#define NKT (KAUG / BK)  // 64 K-tiles, no split-K

static __device__ __forceinline__ unsigned short f2bf(float f) {
  union { float f; unsigned u; } v; v.f = f;
  unsigned r = (v.u + 0x7FFFu + ((v.u >> 16) & 1u)) >> 16;
  return (unsigned short)r;
}

// Merged prep: build_aaug (32768 blocks) + pack_w (4096) + pack_se (256).
__global__ __launch_bounds__(256) void prep(const float* __restrict__ x,
                                            const float* __restrict__ bw,
                                            const float* __restrict__ sw,
                                            const float* __restrict__ w1,
                                            const float* __restrict__ w2,
                                            ushort* __restrict__ Aaug,
                                            ushort* __restrict__ Waug,
                                            ushort* __restrict__ w1b,
                                            ushort* __restrict__ w2b) {
  const int b = blockIdx.x;
  if (b < 32768) {
    const int id = b * 256 + threadIdx.x;  // over NTOK*DIN
    const float v = x[id];
    const float d0 = fabsf(v + 1.f), d1 = fabsf(v), d2 = fabsf(v - 1.f);
    float b0 = (d0 < 1.f) ? (1.f - d0) * (1.f - d0) : 0.f;
    float b1 = (d1 < 1.f) ? (1.f - d1) * (1.f - d1) : 0.f;
    float b2 = (d2 < 1.f) ? (1.f - d2) * (1.f - d2) : 0.f;
    const float inv = 1.f / (b0 + b1 + b2 + 1e-6f);
    ushort4 o;
    o.x = f2bf(v);
    o.y = f2bf(b0 * inv);
    o.z = f2bf(b1 * inv);
    o.w = f2bf(b2 * inv);
    ((ushort4*)Aaug)[id] = o;
  } else if (b < 32768 + 4096) {
    const int id = (b - 32768) * 256 + threadIdx.x;  // over DOUT*DIN
    ushort4 o;
    o.x = f2bf(bw[id]);
    o.y = f2bf(sw[id * 3 + 0]);
    o.z = f2bf(sw[id * 3 + 1]);
    o.w = f2bf(sw[id * 3 + 2]);
    ((ushort4*)Waug)[id] = o;
  } else {
    const int id = (b - 32768 - 4096) * 256 + threadIdx.x;  // 0..65535
    if (id < SEH * DOUT) w1b[id] = f2bf(w1[id]);
    else w2b[id - SEH * DOUT] = f2bf(w2[id - SEH * DOUT]);
  }
}

#define WAITVM(N) asm volatile("s_waitcnt vmcnt(" #N ")" ::: "memory")

// Full-K GEMM: C = A[8192x4096] * B[1024x4096]^T, f32 out direct to d_out.
// 128x128 tile, 4 waves (2Mx2N, per-wave 64x64 = acc[4][4]), BK=64,
// double-buffered 64KB LDS -> 2 blocks/CU. R5/R7-validated sync skeleton:
// STAGE_ALL at tile top -> counted vmcnt(8) -> barrier -> reads -> MFMA -> barrier.
__global__ __launch_bounds__(256, 2) void gemm_ns(const ushort* __restrict__ A,
                                                  const ushort* __restrict__ B,
                                                  float* __restrict__ C) {
  __shared__ ushort As[2][128 * BK];  // 2 x 16 KB
  __shared__ ushort Bs[2][128 * BK];  // 2 x 16 KB
  const int tid = threadIdx.x;
  const int wid = tid >> 6, lane = tid & 63;
  const int l16 = lane & 15, lk = lane >> 4;
  const int wm = wid >> 1, wn = wid & 1;  // 2M x 2N wave grid

  // T1: XCD chunked swizzle (512 blocks, 64 per XCD; bn inner -> A-panel reuse)
  const int g = (blockIdx.x & 7) * 64 + (blockIdx.x >> 3);
  const int bm = g >> 3;  // 0..63
  const int bn = g & 7;   // 0..7

  const ushort* Ab = A + (size_t)bm * 128 * KAUG;
  const ushort* Bb = B + (size_t)bn * 128 * KAUG;

  const int lrow = lane >> 3;         // 0..7
  const int lcb = (lane & 7) ^ lrow;  // inverse-swizzled source col-block

  // ds_read lane constants (element units): index = base + m*1024 + sw(kk)
  // physical chunk = (kk*4+lk) ^ (l16&7); sw1 = sw0 ^ 32  [verified algebra]
  const int aBase = (wm * 64 + l16) * 64;
  const int bBase = (wn * 64 + l16) * 64;
  const int sw0 = ((l16 & 4) << 3) + ((lk ^ (l16 & 3)) << 3);
  const int sw1 = sw0 ^ 32;

  f32x4 acc[4][4] = {};

#define STAGE_A(kt, buf, r)                                                     \
  __builtin_amdgcn_global_load_lds(                                             \
      (const __attribute__((address_space(1))) void*)(Ab +                      \
          (size_t)((r) * 32 + wid * 8 + lrow) * KAUG + (kt) * BK + lcb * 8),    \
      (__attribute__((address_space(3))) void*)(&As[buf][((r) * 256 + wid * 64) * 8]), \
      16, 0, 0)
#define STAGE_B(kt, buf, r)                                                     \
  __builtin_amdgcn_global_load_lds(                                             \
      (const __attribute__((address_space(1))) void*)(Bb +                      \
          (size_t)((r) * 32 + wid * 8 + lrow) * KAUG + (kt) * BK + lcb * 8),    \
      (__attribute__((address_space(3))) void*)(&Bs[buf][((r) * 256 + wid * 64) * 8]), \
      16, 0, 0)
#define STAGE_ALL(kt, buf)                                                      \
  do {                                                                          \
    STAGE_A(kt, buf, 0); STAGE_A(kt, buf, 1); STAGE_A(kt, buf, 2); STAGE_A(kt, buf, 3); \
    STAGE_B(kt, buf, 0); STAGE_B(kt, buf, 1); STAGE_B(kt, buf, 2); STAGE_B(kt, buf, 3); \
  } while (0)

  // One K-tile: CB = compute buffer (compile-time), NB = stage buffer.
#define TILE(kt, CB, NB)                                                        \
  do {                                                                          \
    if ((kt) < NKT - 1) {                                                       \
      STAGE_ALL((kt) + 1, NB);                                                  \
      WAITVM(8);                                                                \
    } else {                                                                    \
      WAITVM(0);                                                                \
    }                                                                           \
    __builtin_amdgcn_s_barrier();                                               \
    __builtin_amdgcn_sched_barrier(0);                                          \
    bf16x8 af[4][2], bfr[4][2];                                                 \
    _Pragma("unroll")                                                           \
    for (int m = 0; m < 4; ++m) {                                               \
      af[m][0] = *(const bf16x8*)&As[CB][aBase + m * 1024 + sw0];               \
      af[m][1] = *(const bf16x8*)&As[CB][aBase + m * 1024 + sw1];               \
    }                                                                           \
    _Pragma("unroll")                                                           \
    for (int n = 0; n < 4; ++n) {                                               \
      bfr[n][0] = *(const bf16x8*)&Bs[CB][bBase + n * 1024 + sw0];              \
      bfr[n][1] = *(const bf16x8*)&Bs[CB][bBase + n * 1024 + sw1];              \
    }                                                                           \
    __builtin_amdgcn_s_setprio(1);                                              \
    _Pragma("unroll")                                                           \
    for (int k2 = 0; k2 < 2; ++k2)                                              \
      _Pragma("unroll")                                                         \
      for (int m = 0; m < 4; ++m)                                               \
        _Pragma("unroll")                                                       \
        for (int n = 0; n < 4; ++n)                                             \
          acc[m][n] = __builtin_amdgcn_mfma_f32_16x16x32_bf16(                  \
              af[m][k2], bfr[n][k2], acc[m][n], 0, 0, 0);                       \
    __builtin_amdgcn_s_setprio(0);                                              \
    __builtin_amdgcn_s_barrier();                                               \
  } while (0)

  // prologue: stage tile 0 into buf 0
  STAGE_ALL(0, 0);

  for (int kt2 = 0; kt2 < NKT; kt2 += 2) {
    TILE(kt2, 0, 1);
    TILE(kt2 + 1, 1, 0);
  }

  // C/D layout: col = lane&15, row = (lane>>4)*4 + reg; f32 stores (64B sectors)
  float* Cb = C + (size_t)(bm * 128 + wm * 64) * DOUT + bn * 128 + wn * 64;
#pragma unroll
  for (int m = 0; m < 4; ++m)
#pragma unroll
    for (int n = 0; n < 4; ++n)
#pragma unroll
      for (int j = 0; j < 4; ++j)
        Cb[(size_t)(m * 16 + lk * 4 + j) * DOUT + n * 16 + l16] = acc[m][n][j];
}

// Fused LayerNorm + SE (both SE matmuls on MFMA). 16 tokens/block, 4 waves.
// In-place on out (f32). Y kept f32 in LDS; weights bf16 read from L2.
__global__ __launch_bounds__(256) void ln_se_mfma(
    float* __restrict__ out,
    const float* __restrict__ ln_w, const float* __restrict__ ln_b,
    const ushort* __restrict__ w1b, const float* __restrict__ se_b1,
    const ushort* __restrict__ w2b, const float* __restrict__ se_b2) {
  __shared__ float Yl[16 * 1028];       // 16 tokens x 1024 (+4 pad) f32
  __shared__ float Hpart[4][512];       // per-wave SE1 partials (16x32)
  __shared__ unsigned Hb[256];          // H packed bf16 [16 tok][16 u32]
  const int tid = threadIdx.x;
  const int w = tid >> 6, lane = tid & 63;
  const int l16 = lane & 15, lk = lane >> 4;
  const int tok0 = blockIdx.x * 16;

  float lw[16], lb[16];
#pragma unroll
  for (int e = 0; e < 16; ++e) {
    lw[e] = ln_w[e * 64 + lane];
    lb[e] = ln_b[e * 64 + lane];
  }

  for (int q = 0; q < 4; ++q) {
    const int tl = w * 4 + q;
    const float* r0 = out + (size_t)(tok0 + tl) * DOUT;
    float v[16];
#pragma unroll
    for (int e = 0; e < 16; ++e) v[e] = r0[e * 64 + lane];
    float s = 0.f, ss = 0.f;
#pragma unroll
    for (int e = 0; e < 16; ++e) { s += v[e]; ss += v[e] * v[e]; }
#pragma unroll
    for (int m = 32; m; m >>= 1) { s += __shfl_xor(s, m); ss += __shfl_xor(ss, m); }
    const float mu = s * (1.f / (float)DOUT);
    const float inv = rsqrtf(ss * (1.f / (float)DOUT) - mu * mu + 1e-5f);
#pragma unroll
    for (int e = 0; e < 16; ++e)
      Yl[tl * 1028 + e * 64 + lane] = (v[e] - mu) * inv * lw[e] + lb[e];
  }
  __syncthreads();

  // SE1: H[16 tok][32 hid] = Y[16][1024] @ w1^T. K split across waves (256 each).
  f32x4 acc1[2] = {};
#pragma unroll
  for (int s = 0; s < 8; ++s) {
    const int ks = w * 8 + s;
    const int k = ks * 32 + lk * 8;
    const float* yp = &Yl[l16 * 1028 + k];
    const f32x4 q0 = *(const f32x4*)yp;
    const f32x4 q1 = *(const f32x4*)(yp + 4);
    bf16x8 af;
    af[0] = (__bf16)q0[0]; af[1] = (__bf16)q0[1];
    af[2] = (__bf16)q0[2]; af[3] = (__bf16)q0[3];
    af[4] = (__bf16)q1[0]; af[5] = (__bf16)q1[1];
    af[6] = (__bf16)q1[2]; af[7] = (__bf16)q1[3];
#pragma unroll
    for (int nt = 0; nt < 2; ++nt) {
      const bf16x8 bf = *(const bf16x8*)(w1b + (nt * 16 + l16) * 1024 + ks * 32 + lk * 8);
      acc1[nt] = __builtin_amdgcn_mfma_f32_16x16x32_bf16(af, bf, acc1[nt], 0, 0, 0);
    }
  }
#pragma unroll
  for (int nt = 0; nt < 2; ++nt)
#pragma unroll
    for (int j = 0; j < 4; ++j)
      Hpart[w][(lk * 4 + j) * 32 + nt * 16 + l16] = acc1[nt][j];
  __syncthreads();

  {
    const int e2 = tid * 2;
    float h0 = Hpart[0][e2] + Hpart[1][e2] + Hpart[2][e2] + Hpart[3][e2];
    float h1 = Hpart[0][e2 + 1] + Hpart[1][e2 + 1] + Hpart[2][e2 + 1] + Hpart[3][e2 + 1];
    h0 = fmaxf(h0 + se_b1[e2 & 31], 0.f);
    h1 = fmaxf(h1 + se_b1[(e2 & 31) + 1], 0.f);
    Hb[tid] = (unsigned)f2bf(h0) | ((unsigned)f2bf(h1) << 16);
  }
  __syncthreads();

  // SE2: G[16 tok][1024] = H[16][32] @ w2^T, N split across waves (256 each).
  union { uint4 u; bf16x8 v; } ha;
  ha.u = *(const uint4*)&Hb[l16 * 16 + lk * 4];
  const int nbase = w * 256;
#pragma unroll
  for (int nt = 0; nt < 16; ++nt) {
    const int col = nbase + nt * 16 + l16;
    const bf16x8 bf = *(const bf16x8*)(w2b + col * 32 + lk * 8);
    f32x4 gz = {0.f, 0.f, 0.f, 0.f};
    gz = __builtin_amdgcn_mfma_f32_16x16x32_bf16(ha.v, bf, gz, 0, 0, 0);
    const float b2 = se_b2[col];
#pragma unroll
    for (int j = 0; j < 4; ++j) {
      const int tl = lk * 4 + j;
      const float sg = 1.f / (1.f + __expf(-(gz[j] + b2)));
      out[(size_t)(tok0 + tl) * DOUT + col] = Yl[tl * 1028 + col] * sg;
    }
  }
}

extern "C" void kernel_launch(void* const* d_in, const int* in_sizes, int n_in,
                              void* d_out, int out_size, void* d_ws, size_t ws_size,
                              hipStream_t stream) {
  const float* x = (const float*)d_in[0];
  const float* bw = (const float*)d_in[1];
  const float* sw = (const float*)d_in[2];
  const float* ln_w = (const float*)d_in[3];
  const float* ln_b = (const float*)d_in[4];
  const float* se_w1 = (const float*)d_in[5];
  const float* se_b1 = (const float*)d_in[6];
  const float* se_w2 = (const float*)d_in[7];
  const float* se_b2 = (const float*)d_in[8];
  float* out = (float*)d_out;

  ushort* Aaug = (ushort*)d_ws;                        // 64 MB
  ushort* Waug = Aaug + (size_t)NTOK * KAUG;           // 8 MB
  ushort* w1b = Waug + (size_t)DOUT * KAUG;            // 64 KB
  ushort* w2b = w1b + SEH * DOUT;                      // 64 KB

  prep<<<32768 + 4096 + 256, 256, 0, stream>>>(x, bw, sw, se_w1, se_w2,
                                               Aaug, Waug, w1b, w2b);
  gemm_ns<<<512, 256, 0, stream>>>(Aaug, Waug, out);
  ln_se_mfma<<<NTOK / 16, 256, 0, stream>>>(out, ln_w, ln_b,
                                            w1b, se_b1, w2b, se_b2);
}